// Round 1
// baseline (394.208 us; speedup 1.0000x reference)
//
#include <hip/hip_runtime.h>

// Masked 3x3 conv as implicit GEMM, bf16 MFMA (m97-style structure).
//   C[f][n] = sum_{tap,c} Wt[f][tap*512+c] * Xt[(h+dh)*194+(w+dw)][c]
//   out = C*mask + bias
// Layouts:
//   Xt: padded channels-last bf16 [194][194][512], zero halo (pad=1)
//   Wt: bf16 [512][9*512], k = tap*512 + c  (k-contiguous, like W row-major)
// GEMM: M=512 (f), N=36864 (pixels), K=4608. 128x128 tile, BK=32,
// 256 threads = 4 waves, each wave 64x64 via 4x4 mfma_f32_16x16x32_bf16.

typedef unsigned short ushort_t;
typedef __attribute__((ext_vector_type(8))) __bf16 bf16x8;
typedef __attribute__((ext_vector_type(4))) float f32x4;
typedef __attribute__((ext_vector_type(8))) unsigned short ushort8;

#define IMG_W 192
#define IMG_H 192
#define HW    36864       // 192*192
#define PAD_W 194
#define C_IN  512
#define F_OUT 512
#define KTOT  4608        // 9*512

__device__ __forceinline__ unsigned short f2bf(float f) {
  // round-to-nearest-even fp32 -> bf16 (no NaN inputs in this problem)
  unsigned int u = __builtin_bit_cast(unsigned int, f);
  u += 0x7fffu + ((u >> 16) & 1u);
  return (unsigned short)(u >> 16);
}

__device__ __forceinline__ void async16(const void* g, void* l) {
  // 16B/lane global->LDS DMA; LDS dest is wave-uniform base + lane*16
  __builtin_amdgcn_global_load_lds(
      (const __attribute__((address_space(1))) unsigned int*)g,
      (__attribute__((address_space(3))) unsigned int*)l, 16, 0, 0);
}

// ---------------- prep: x NCHW fp32 -> padded NHWC bf16 ----------------
// grid (3 wtiles, 8 ctiles, 192 h), block 256. LDS-tiled 64c x 64w transpose.
__global__ void prep_x(const float* __restrict__ x, ushort_t* __restrict__ Xt) {
  __shared__ float tile[64][65];   // +1 pad: conflict-free
  const int tid = threadIdx.x;
  const int h  = blockIdx.z;
  const int w0 = blockIdx.x * 64;
  const int c0 = blockIdx.y * 64;

  // load: 64 consecutive w per 64-lane row group (coalesced 256B)
  const int wl_r = tid & 63;
  const int cg_r = tid >> 6;       // 0..3, 16 channels each
  const float* src = x + (size_t)(c0 + cg_r * 16) * HW + (size_t)h * IMG_W + w0 + wl_r;
#pragma unroll
  for (int cc = 0; cc < 16; ++cc)
    tile[cg_r * 16 + cc][wl_r] = src[(size_t)cc * HW];
  __syncthreads();

  // store: per (w), 64 consecutive c -> contiguous bf16 (two 16B stores)
  const int wl = tid >> 2;         // 0..63
  const int cg = tid & 3;          // 16 channels each
  ushort_t* dst = Xt + ((size_t)(h + 1) * PAD_W + (w0 + wl + 1)) * C_IN + c0 + cg * 16;
  ushort8 v0, v1;
#pragma unroll
  for (int cc = 0; cc < 8; ++cc) v0[cc] = f2bf(tile[cg * 16 + cc][wl]);
#pragma unroll
  for (int cc = 0; cc < 8; ++cc) v1[cc] = f2bf(tile[cg * 16 + 8 + cc][wl]);
  *(ushort8*)dst = v0;
  *(ushort8*)(dst + 8) = v1;
}

// ---------------- prep: w [f][c][kh][kw] fp32 -> Wt [f][tap*512+c] bf16 ----
__global__ void prep_w(const float* __restrict__ w, ushort_t* __restrict__ Wt) {
  int idx = blockIdx.x * 256 + threadIdx.x;     // = f*4608 + tap*512 + c
  if (idx < F_OUT * KTOT) {
    int f   = idx / KTOT;
    int rem = idx - f * KTOT;
    int tap = rem >> 9;
    int c   = rem & 511;
    Wt[idx] = f2bf(w[(size_t)f * KTOT + c * 9 + tap]);   // w[f][c][kh][kw], tap=kh*3+kw
  }
}

// ---------------- implicit GEMM + mask/bias epilogue ----------------
__global__ __launch_bounds__(256) void conv_gemm(
    const ushort_t* __restrict__ Wt, const ushort_t* __restrict__ Xt,
    const float* __restrict__ bias, const int* __restrict__ mask,
    float* __restrict__ out) {
  __shared__ __align__(16) ushort_t As[128 * 32];  // [m 0..127][k 0..31]
  __shared__ __align__(16) ushort_t Bs[128 * 32];  // [n 0..127][k 0..31]

  const int tid  = threadIdx.x;
  const int lane = tid & 63;
  const int wave = tid >> 6;
  const int wm   = wave >> 1;      // wave's 64-row block
  const int wn   = wave & 1;       // wave's 64-col block
  const int m0   = blockIdx.y * 128;
  const int n0   = blockIdx.x * 128;

  // staging roles: thread -> (row = tid>>2 [+64 for 2nd issue], k-quad = tid&3)
  const int nl = tid >> 2;
  const int kq = tid & 3;
  const int n_a = n0 + nl;
  const int n_b = n_a + 64;
  const int ha = n_a / IMG_W, wa = n_a - ha * IMG_W;
  const int hb = n_b / IMG_W, wb = n_b - hb * IMG_W;
  const ushort_t* bSrcA = Xt + ((size_t)(ha + 1) * PAD_W + (wa + 1)) * C_IN + kq * 8;
  const ushort_t* bSrcB = Xt + ((size_t)(hb + 1) * PAD_W + (wb + 1)) * C_IN + kq * 8;
  const ushort_t* aSrcA = Wt + (size_t)(m0 + nl) * KTOT + kq * 8;
  const ushort_t* aSrcB = aSrcA + (size_t)64 * KTOT;

  // wave-uniform LDS dest bases (HW adds lane*16B)
  ushort_t* aDstA = &As[wave * 512];
  ushort_t* aDstB = &As[2048 + wave * 512];
  ushort_t* bDstA = &Bs[wave * 512];
  ushort_t* bDstB = &Bs[2048 + wave * 512];

  f32x4 acc[4][4] = {};

  const int col  = lane & 15;
  const int quad = lane >> 4;
  const int aOff = (wm * 64 + col) * 32 + quad * 8;  // + i*512 per m-subtile
  const int bOff = (wn * 64 + col) * 32 + quad * 8;  // + j*512 per n-subtile

#pragma unroll 1
  for (int tap = 0; tap < 9; ++tap) {
    const int toff = ((tap / 3) * PAD_W + (tap % 3) - (PAD_W + 1)) * C_IN;  // (dh-1,dw-1) shift
    const ushort_t* bA = bSrcA + toff;
    const ushort_t* bB = bSrcB + toff;
    const ushort_t* aA = aSrcA + tap * 512;
    const ushort_t* aB = aSrcB + tap * 512;
#pragma unroll 1
    for (int kc = 0; kc < 512; kc += 32) {
      async16(aA + kc, aDstA);
      async16(aB + kc, aDstB);
      async16(bA + kc, bDstA);
      async16(bB + kc, bDstB);
      __syncthreads();   // drains vmcnt for the async LDS loads

      bf16x8 af[4], bfr[4];
#pragma unroll
      for (int i = 0; i < 4; ++i) af[i]  = *(const bf16x8*)&As[aOff + i * 512];
#pragma unroll
      for (int j = 0; j < 4; ++j) bfr[j] = *(const bf16x8*)&Bs[bOff + j * 512];
#pragma unroll
      for (int i = 0; i < 4; ++i)
#pragma unroll
        for (int j = 0; j < 4; ++j)
          acc[i][j] = __builtin_amdgcn_mfma_f32_16x16x32_bf16(af[i], bfr[j], acc[i][j], 0, 0, 0);
      __syncthreads();
    }
  }

  // epilogue: out = acc*mask + bias   (C/D layout: col=lane&15, row=quad*4+r)
#pragma unroll
  for (int j = 0; j < 4; ++j) {
    const int n = n0 + wn * 64 + j * 16 + col;
    const float mv = (float)mask[n];
#pragma unroll
    for (int i = 0; i < 4; ++i) {
      const int mrow = m0 + wm * 64 + i * 16 + quad * 4;
      float* o = out + (size_t)mrow * HW + n;
#pragma unroll
      for (int r = 0; r < 4; ++r)
        o[(size_t)r * HW] = acc[i][j][r] * mv + bias[mrow + r];
    }
  }
}

extern "C" void kernel_launch(void* const* d_in, const int* in_sizes, int n_in,
                              void* d_out, int out_size, void* d_ws, size_t ws_size,
                              hipStream_t stream) {
  const float* x    = (const float*)d_in[0];  // [512][192][192]
  const float* w    = (const float*)d_in[1];  // [512][512][3][3]
  const float* bias = (const float*)d_in[2];  // [512]
  const int*   mask = (const int*)d_in[3];    // [192][192]
  float* out = (float*)d_out;                 // [512][192][192]

  ushort_t* Xt = (ushort_t*)d_ws;                                   // 194*194*512 bf16
  ushort_t* Wt = (ushort_t*)d_ws + (size_t)PAD_W * PAD_W * C_IN;    // 512*4608 bf16
  // ws need: 38.54 MB + 4.72 MB = 43.3 MB

  hipMemsetAsync(Xt, 0, (size_t)PAD_W * PAD_W * C_IN * sizeof(ushort_t), stream);
  prep_x<<<dim3(3, 8, 192), 256, 0, stream>>>(x, Xt);
  prep_w<<<dim3((F_OUT * KTOT) / 256), 256, 0, stream>>>(w, Wt);
  conv_gemm<<<dim3(HW / 128, F_OUT / 128), 256, 0, stream>>>(Wt, Xt, bias, mask, out);
}